// Round 1
// baseline (834.701 us; speedup 1.0000x reference)
//
#include <hip/hip_runtime.h>
#include <stdint.h>

typedef unsigned short u16;
typedef __bf16 bf16x8 __attribute__((ext_vector_type(8)));
typedef float f32x4 __attribute__((ext_vector_type(4)));

__device__ __forceinline__ u16 f32_bf16_rn(float f) {
  uint32_t u = __float_as_uint(f);
  uint32_t r = (u + 0x7FFFu + ((u >> 16) & 1u)) >> 16;
  return (u16)r;
}
__device__ __forceinline__ float bf16_f32(u16 h) {
  return __uint_as_float(((uint32_t)h) << 16);
}

// async global->LDS, 16B per lane. LDS dest = wave-uniform base + lane*16.
__device__ __forceinline__ void async16(const u16* g, u16* l) {
  __builtin_amdgcn_global_load_lds(
      (__attribute__((address_space(1))) void*)(g),
      (__attribute__((address_space(3))) void*)(l), 16, 0, 0);
}

// ---------------------------------------------------------------------------
// split3: f32 [R][2048] (row stride ldin) -> bf16 [R][3*2048]
// PAT 0: [hi | lo | hi]  (A operand)   PAT 1: [hi | hi | lo]  (B operand)
// ---------------------------------------------------------------------------
template<int PAT>
__global__ __launch_bounds__(256)
void split3(const float* __restrict__ in, u16* __restrict__ out, int R, int ldin) {
  size_t total = (size_t)R * 2048;
  size_t stride = (size_t)gridDim.x * blockDim.x;
  for (size_t idx = (size_t)blockIdx.x * blockDim.x + threadIdx.x; idx < total; idx += stride) {
    int r = (int)(idx >> 11);
    int c = (int)(idx & 2047);
    float f = in[(size_t)r * ldin + c];
    u16 hi = f32_bf16_rn(f);
    u16 lo = f32_bf16_rn(f - bf16_f32(hi));
    u16* o = out + (size_t)r * 6144;
    if (PAT == 0) { o[c] = hi; o[2048 + c] = lo; o[4096 + c] = hi; }
    else          { o[c] = hi; o[2048 + c] = hi; o[4096 + c] = lo; }
  }
}

// plain f32 -> bf16 cast, 4-wide
__global__ __launch_bounds__(256)
void cast_bf16_k(const float* __restrict__ in, u16* __restrict__ out, int n4) {
  int stride = gridDim.x * blockDim.x;
  for (int i = blockIdx.x * blockDim.x + threadIdx.x; i < n4; i += stride) {
    float4 f = ((const float4*)in)[i];
    ushort4 o;
    o.x = f32_bf16_rn(f.x); o.y = f32_bf16_rn(f.y);
    o.z = f32_bf16_rn(f.z); o.w = f32_bf16_rn(f.w);
    ((ushort4*)out)[i] = o;
  }
}

// transpose+cast: out[c][r] = bf16(in[r][c]), R=4096 rows, C=2048 cols via grid
__global__ __launch_bounds__(256)
void transpose_cast(const float* __restrict__ in, u16* __restrict__ out, int ldin, int ldout) {
  __shared__ float tile[32][33];
  int c0 = blockIdx.x * 32, r0 = blockIdx.y * 32;
  int tx = threadIdx.x, ty = threadIdx.y;  // (32,8)
#pragma unroll
  for (int i = 0; i < 32; i += 8)
    tile[ty + i][tx] = in[(size_t)(r0 + ty + i) * ldin + c0 + tx];
  __syncthreads();
#pragma unroll
  for (int i = 0; i < 32; i += 8)
    out[(size_t)(c0 + ty + i) * ldout + r0 + tx] = f32_bf16_rn(tile[tx][ty + i]);
}

// ---------------------------------------------------------------------------
// causal row softmax: S f32 [4096][4096] -> P bf16, row i valid cols 0..i,
// zero-fill up to next 128 boundary (PV gemm K-limits there).
// ---------------------------------------------------------------------------
__device__ __forceinline__ float waveMax(float v) {
#pragma unroll
  for (int o = 32; o > 0; o >>= 1) v = fmaxf(v, __shfl_xor(v, o));
  return v;
}
__device__ __forceinline__ float waveSum(float v) {
#pragma unroll
  for (int o = 32; o > 0; o >>= 1) v += __shfl_xor(v, o);
  return v;
}

__global__ __launch_bounds__(256)
void softmax_causal(const float* __restrict__ S, u16* __restrict__ P, int L) {
  int row = blockIdx.x;
  int tid = threadIdx.x;
  int wave = tid >> 6, lane = tid & 63;
  int n = row + 1;
  int pad = ((row >> 7) + 1) << 7;
  const float* s = S + (size_t)row * L;
  __shared__ float sred[8];

  float m = -3.4e38f;
  for (int j = tid; j < n; j += 256) m = fmaxf(m, s[j]);
  m = waveMax(m);
  if (lane == 0) sred[wave] = m;
  __syncthreads();
  m = fmaxf(fmaxf(sred[0], sred[1]), fmaxf(sred[2], sred[3]));

  float sum = 0.0f;
  for (int j = tid; j < n; j += 256) sum += __expf(s[j] - m);
  sum = waveSum(sum);
  if (lane == 0) sred[4 + wave] = sum;
  __syncthreads();
  sum = sred[4] + sred[5] + sred[6] + sred[7];
  float inv = 1.0f / sum;

  u16* p = P + (size_t)row * L;
  for (int j = tid; j < pad; j += 256) {
    float v = (j < n) ? __expf(s[j] - m) * inv : 0.0f;
    p[j] = f32_bf16_rn(v);
  }
}

// ---------------------------------------------------------------------------
// NT GEMM: C[M][N] = A[M][K] * B[N][K]^T (+bias[n]), bf16 in / f32 out.
// 128x128 tile, BK=64, 4 waves, 4x4 frags of mfma_f32_16x16x32_bf16.
// XOR-swizzled LDS (pre-swizzled global source for linear global_load_lds).
// CAUSAL==1: skip tiles fully above diagonal (M==N).
// CAUSAL==2: K-limit per row-block: Keff = by*128+128 (PV causal).
// ---------------------------------------------------------------------------
template<int CAUSAL, bool HAS_BIAS>
__global__ __launch_bounds__(256)
void gemm_nt(const u16* __restrict__ A, const u16* __restrict__ B,
             float* __restrict__ C, const float* __restrict__ bias,
             int M, int N, int K) {
  constexpr int BM = 128, BN = 128, BK = 64;
  __shared__ u16 As[BM * BK];
  __shared__ u16 Bs[BN * BK];

  int bx = blockIdx.x, by = blockIdx.y;
  if (CAUSAL == 1 && bx * BN >= by * BM + BM) return;
  int Keff = (CAUSAL == 2) ? (by * BM + BM) : K;

  int tid = threadIdx.x;
  int wave = tid >> 6, lane = tid & 63;
  int wr = wave >> 1, wc = wave & 1;

  // staging: per issue `it`, this wave loads rows it*32 + wave*8 + (lane>>3),
  // physical 16B slot (lane&7); global column group pre-swizzled by row&7.
  int srow = lane >> 3;                     // 0..7 ; == row&7 (row base % 8 == 0)
  int scol = ((lane & 7) ^ srow) << 3;      // swizzled source column (elements)
  const u16* Ag = A + (size_t)(by * BM + wave * 8 + srow) * K + scol;
  const u16* Bg = B + (size_t)(bx * BN + wave * 8 + srow) * K + scol;
  u16* AsW = As + wave * 8 * BK;
  u16* BsW = Bs + wave * 8 * BK;

  f32x4 zero = {0.0f, 0.0f, 0.0f, 0.0f};
  f32x4 acc[4][4];
#pragma unroll
  for (int i = 0; i < 4; ++i)
#pragma unroll
    for (int j = 0; j < 4; ++j) acc[i][j] = zero;

  for (int k0 = 0; k0 < Keff; k0 += BK) {
#pragma unroll
    for (int it = 0; it < 4; ++it) {
      async16(Ag + (size_t)it * 32 * K + k0, AsW + it * 32 * BK);
      async16(Bg + (size_t)it * 32 * K + k0, BsW + it * 32 * BK);
    }
    __syncthreads();  // drains vmcnt before barrier

#pragma unroll
    for (int kk = 0; kk < 2; ++kk) {
      bf16x8 af[4], bb[4];
      int col = lane & 15;
      int sl = kk * 4 + (lane >> 4);        // logical 16B slot (k-group of 8)
#pragma unroll
      for (int mi = 0; mi < 4; ++mi) {
        int row = wr * 64 + mi * 16 + col;
        af[mi] = *(const bf16x8*)&As[row * BK + ((sl ^ (row & 7)) << 3)];
      }
#pragma unroll
      for (int ni = 0; ni < 4; ++ni) {
        int row = wc * 64 + ni * 16 + col;
        bb[ni] = *(const bf16x8*)&Bs[row * BK + ((sl ^ (row & 7)) << 3)];
      }
#pragma unroll
      for (int mi = 0; mi < 4; ++mi)
#pragma unroll
        for (int ni = 0; ni < 4; ++ni)
          acc[mi][ni] = __builtin_amdgcn_mfma_f32_16x16x32_bf16(
              af[mi], bb[ni], acc[mi][ni], 0, 0, 0);
    }
    __syncthreads();  // before next staging overwrites LDS
  }

  // epilogue: D layout col = lane&15, row = (lane>>4)*4 + r
  int r0 = by * BM + wr * 64 + ((lane >> 4) << 2);
  int c0 = bx * BN + wc * 64 + (lane & 15);
#pragma unroll
  for (int mi = 0; mi < 4; ++mi)
#pragma unroll
    for (int ni = 0; ni < 4; ++ni) {
      int cc = c0 + ni * 16;
      float bv = HAS_BIAS ? bias[cc] : 0.0f;
#pragma unroll
      for (int r = 0; r < 4; ++r)
        C[(size_t)(r0 + mi * 16 + r) * N + cc] = acc[mi][ni][r] + bv;
    }
}

// ---------------------------------------------------------------------------
extern "C" void kernel_launch(void* const* d_in, const int* in_sizes, int n_in,
                              void* d_out, int out_size, void* d_ws, size_t ws_size,
                              hipStream_t stream) {
  (void)in_sizes; (void)n_in; (void)out_size; (void)ws_size;
  const float* x     = (const float*)d_in[0];  // [4096][2048]
  const float* Wqkv  = (const float*)d_in[1];  // [6144][2048]
  const float* bqkv  = (const float*)d_in[2];  // [6144]
  const float* Wproj = (const float*)d_in[3];  // [2048][2048]
  const float* bproj = (const float*)d_in[4];  // [2048]
  float* out = (float*)d_out;                  // [4096][2048]

  char* w = (char*)d_ws;
  const size_t OFF1 = 50331648;   // 4096*6144*2
  const size_t OFF2 = 125829120;  // OFF1 + 6144*6144*2
  u16*   x3   = (u16*)w;                          // [4096][6144] bf16
  u16*   W3   = (u16*)(w + OFF1);                 // [6144][6144] bf16
  float* qkv  = (float*)(w + OFF2);               // [4096][6144] f32
  u16*   q3   = x3;                               // reuse (x3 dead)
  u16*   k3   = W3;                               // reuse (W3 dead)
  u16*   vT   = (u16*)(w + OFF1 + 50331648);      // [2048][4096] bf16
  float* Smat = qkv;                              // [4096][4096] f32 (qkv dead)
  u16*   P    = (u16*)(w + OFF2 + 67108864);      // [4096][4096] bf16
  float* attn = (float*)w;                        // [4096][2048] f32 (q3 dead)
  u16*   ao   = (u16*)(w + OFF1);                 // [4096][2048] bf16 (k3 dead)
  u16*   Wp   = (u16*)(w + OFF1 + 16777216);      // [2048][2048] bf16

  // 1) QKV projection: qkv = x @ Wqkv^T + bqkv (3-term split bf16)
  split3<0><<<2048, 256, 0, stream>>>(x,    x3, 4096, 2048);
  split3<1><<<2048, 256, 0, stream>>>(Wqkv, W3, 6144, 2048);
  gemm_nt<0, true><<<dim3(48, 32), 256, 0, stream>>>(x3, W3, qkv, bqkv, 4096, 6144, 6144);

  // 2) build split q/k and transposed v
  split3<1><<<2048, 256, 0, stream>>>(qkv,        q3, 4096, 6144);  // B operand
  split3<0><<<2048, 256, 0, stream>>>(qkv + 2048, k3, 4096, 6144);  // A operand
  transpose_cast<<<dim3(64, 128), dim3(32, 8), 0, stream>>>(qkv + 4096, vT, 6144, 4096);

  // 3) S = k @ q^T (causal tiles only), softmax rows -> P (bf16)
  gemm_nt<1, false><<<dim3(32, 32), 256, 0, stream>>>(k3, q3, Smat, nullptr, 4096, 4096, 6144);
  softmax_causal<<<4096, 256, 0, stream>>>(Smat, P, 4096);

  // 4) attn = P @ v  (K-limited per row block)
  gemm_nt<2, false><<<dim3(16, 32), 256, 0, stream>>>(P, vT, attn, nullptr, 4096, 2048, 4096);

  // 5) out = attn @ Wproj^T + bproj (single bf16 is enough here)
  cast_bf16_k<<<1024, 256, 0, stream>>>(attn,  ao, 4096 * 2048 / 4);
  cast_bf16_k<<<1024, 256, 0, stream>>>(Wproj, Wp, 2048 * 2048 / 4);
  gemm_nt<0, true><<<dim3(16, 32), 256, 0, stream>>>(ao, Wp, out, bproj, 4096, 2048, 2048);
}

// Round 2
// 757.732 us; speedup vs baseline: 1.1016x; 1.1016x over previous
//
#include <hip/hip_runtime.h>
#include <stdint.h>

typedef unsigned short u16;
typedef __bf16 bf16x8 __attribute__((ext_vector_type(8)));
typedef float f32x4 __attribute__((ext_vector_type(4)));

__device__ __forceinline__ u16 f32_bf16_rn(float f) {
  uint32_t u = __float_as_uint(f);
  uint32_t r = (u + 0x7FFFu + ((u >> 16) & 1u)) >> 16;
  return (u16)r;
}
__device__ __forceinline__ float bf16_f32(u16 h) {
  return __uint_as_float(((uint32_t)h) << 16);
}

// async global->LDS, 16B per lane. LDS dest = wave-uniform base + lane*16.
__device__ __forceinline__ void async16(const u16* g, u16* l) {
  __builtin_amdgcn_global_load_lds(
      (__attribute__((address_space(1))) void*)(g),
      (__attribute__((address_space(3))) void*)(l), 16, 0, 0);
}

// f32 [R][2048] -> bf16 [R][4096] as [hi | lo]
__global__ __launch_bounds__(256)
void split2(const float* __restrict__ in, u16* __restrict__ out, size_t total) {
  size_t stride = (size_t)gridDim.x * blockDim.x;
  for (size_t idx = (size_t)blockIdx.x * blockDim.x + threadIdx.x; idx < total; idx += stride) {
    int r = (int)(idx >> 11);
    int c = (int)(idx & 2047);
    float f = in[idx];
    u16 hi = f32_bf16_rn(f);
    u16 lo = f32_bf16_rn(f - bf16_f32(hi));
    out[(size_t)r * 4096 + c] = hi;
    out[(size_t)r * 4096 + 2048 + c] = lo;
  }
}

__global__ __launch_bounds__(256)
void cast_bf16_k(const float* __restrict__ in, u16* __restrict__ out, int n4) {
  int stride = gridDim.x * blockDim.x;
  for (int i = blockIdx.x * blockDim.x + threadIdx.x; i < n4; i += stride) {
    float4 f = ((const float4*)in)[i];
    ushort4 o;
    o.x = f32_bf16_rn(f.x); o.y = f32_bf16_rn(f.y);
    o.z = f32_bf16_rn(f.z); o.w = f32_bf16_rn(f.w);
    ((ushort4*)out)[i] = o;
  }
}

// ---------------------------------------------------------------------------
// causal row softmax: S f32 [4096][4096] -> P bf16, row i valid cols 0..i,
// zero-fill up to next 128 boundary (PV gemm K-limits there).
// ---------------------------------------------------------------------------
__device__ __forceinline__ float waveMax(float v) {
#pragma unroll
  for (int o = 32; o > 0; o >>= 1) v = fmaxf(v, __shfl_xor(v, o));
  return v;
}
__device__ __forceinline__ float waveSum(float v) {
#pragma unroll
  for (int o = 32; o > 0; o >>= 1) v += __shfl_xor(v, o);
  return v;
}

__global__ __launch_bounds__(256)
void softmax_causal(const float* __restrict__ S, u16* __restrict__ P, int L) {
  int row = blockIdx.x;
  int tid = threadIdx.x;
  int wave = tid >> 6, lane = tid & 63;
  int n = row + 1;
  int pad = ((row >> 7) + 1) << 7;
  const float* s = S + (size_t)row * L;
  __shared__ float sred[8];

  float m = -3.4e38f;
  for (int j = tid; j < n; j += 256) m = fmaxf(m, s[j]);
  m = waveMax(m);
  if (lane == 0) sred[wave] = m;
  __syncthreads();
  m = fmaxf(fmaxf(sred[0], sred[1]), fmaxf(sred[2], sred[3]));

  float sum = 0.0f;
  for (int j = tid; j < n; j += 256) sum += __expf(s[j] - m);
  sum = waveSum(sum);
  if (lane == 0) sred[4 + wave] = sum;
  __syncthreads();
  sum = sred[4] + sred[5] + sred[6] + sred[7];
  float inv = 1.0f / sum;

  u16* p = P + (size_t)row * L;
  for (int j = tid; j < pad; j += 256) {
    float v = (j < n) ? __expf(s[j] - m) * inv : 0.0f;
    p[j] = f32_bf16_rn(v);
  }
}

// ---------------------------------------------------------------------------
// K-remap for the 3-term bf16 split GEMM over physical [hi|lo] storage:
// mode 0: identity. mode 1: [h|l|h] (A side). mode 2: [h|h|l] (B side).
// K-tile t (BK=64), D=2048, logical K=6144, physical ld 4096.
// ---------------------------------------------------------------------------
__device__ __forceinline__ int kmap(int mode, int t) {
  if (mode == 1) return (t < 32) ? t * 64 : (t < 64) ? 2048 + (t - 32) * 64 : (t - 64) * 64;
  if (mode == 2) return (t < 32) ? t * 64 : (t < 64) ? (t - 32) * 64 : 2048 + (t - 64) * 64;
  return t * 64;
}

// ---------------------------------------------------------------------------
// 256x256 8-wave pipelined NT GEMM, BK=64, double-buffered 128KiB LDS,
// 4 phases/K-tile, counted vmcnt (4), XOR-swizzled LDS, setprio around MFMA.
// EPI 0: C f32 (ldc).   EPI 1: QKV epilogue -> q2 [h|l], k2 [h|l], vT (bf16^T), +bias.
// CAUSAL 1: skip tiles with bx > by (M==N grid).
// ---------------------------------------------------------------------------
#define MFMA_PAIR(MI, AF) { \
  _Pragma("unroll") \
  for (int ni = 0; ni < 4; ++ni) { \
    acc[MI][ni] = __builtin_amdgcn_mfma_f32_16x16x32_bf16(AF[0], bfr[ni][0], acc[MI][ni], 0, 0, 0); \
    acc[MI][ni] = __builtin_amdgcn_mfma_f32_16x16x32_bf16(AF[1], bfr[ni][1], acc[MI][ni], 0, 0, 0); \
  } }

template<int EPI, int AMAP, int BMAP, int CAUSAL>
__global__ __launch_bounds__(512, 2)
void gemm_nt2(const u16* __restrict__ A, int lda, const u16* __restrict__ B, int ldb,
              float* __restrict__ C, int ldc,
              u16* __restrict__ q2, u16* __restrict__ k2, u16* __restrict__ vT,
              const float* __restrict__ bias, int K) {
  constexpr int BK = 64;
  __shared__ u16 Asm[2][256 * BK];
  __shared__ u16 Bsm[2][256 * BK];
  const int bx = blockIdx.x, by = blockIdx.y;
  if (CAUSAL == 1 && bx > by) return;
  const int nt = K / BK;   // nt >= 2 in all uses

  const int tid = threadIdx.x;
  const int w = tid >> 6, lane = tid & 63;
  const int wr = w >> 2, wc = w & 3;
  const int srow = lane >> 3;
  const int scol = ((lane & 7) ^ srow) << 3;   // pre-swizzled source column
  const u16* Ag = A + (size_t)(by * 256 + w * 8 + srow) * lda + scol;
  const u16* Bg = B + (size_t)(bx * 256 + w * 8 + srow) * ldb + scol;

#define STG_A(bufi, half, tt) { \
    const int kc_ = kmap(AMAP, tt); \
    const u16* g_ = Ag + (size_t)((half) * 128) * lda + kc_; \
    u16* l_ = &Asm[bufi][((half) * 128 + w * 8) * BK]; \
    async16(g_, l_); \
    async16(g_ + (size_t)64 * lda, l_ + 64 * BK); }
#define STG_B(bufi, half, tt) { \
    const int kc_ = kmap(BMAP, tt); \
    const u16* g_ = Bg + (size_t)((half) * 128) * ldb + kc_; \
    u16* l_ = &Bsm[bufi][((half) * 128 + w * 8) * BK]; \
    async16(g_, l_); \
    async16(g_ + (size_t)64 * ldb, l_ + 64 * BK); }

  const int fcol = lane & 15;
  const int fks = lane >> 4;
  const int rx = fcol & 7;
#define LD8(Sb, rowbase, ks) (*(const bf16x8*)&(Sb)[((rowbase) + fcol) * BK + ((((ks) * 4 + fks) ^ rx) << 3)])

  f32x4 acc[8][4];
#pragma unroll
  for (int i = 0; i < 8; ++i)
#pragma unroll
    for (int j = 0; j < 4; ++j) acc[i][j] = (f32x4){0.f, 0.f, 0.f, 0.f};

  // prologue: tile0 (A+B) + tile1 A  -> 12 loads/wave; drain to 4
  STG_A(0, 0, 0) STG_A(0, 1, 0) STG_B(0, 0, 0) STG_B(0, 1, 0)
  STG_A(1, 0, 1) STG_A(1, 1, 1)
  asm volatile("s_waitcnt vmcnt(4)" ::: "memory");
  asm volatile("s_barrier" ::: "memory");

  for (int t = 0; t < nt; ++t) {
    const int buf = t & 1;
    const u16* As = Asm[buf];
    const u16* Bs = Bsm[buf];
    const int ar = wr * 128;
    bf16x8 bfr[4][2];
    bf16x8 a0[2], a1[2], a2[2], a3[2], a4[2], a5[2];

    // ---- phase a: B-frags + A rows 0-1; MFMA rows 0-1 ----
    if (t + 1 < nt) STG_B(buf ^ 1, 0, t + 1)
#pragma unroll
    for (int ni = 0; ni < 4; ++ni) {
      bfr[ni][0] = LD8(Bs, wc * 64 + ni * 16, 0);
      bfr[ni][1] = LD8(Bs, wc * 64 + ni * 16, 1);
    }
    a0[0] = LD8(As, ar + 0, 0);  a0[1] = LD8(As, ar + 0, 1);
    a1[0] = LD8(As, ar + 16, 0); a1[1] = LD8(As, ar + 16, 1);
    asm volatile("s_barrier" ::: "memory");
    __builtin_amdgcn_s_setprio(1);
    MFMA_PAIR(0, a0) MFMA_PAIR(1, a1)
    __builtin_amdgcn_s_setprio(0);
    asm volatile("s_barrier" ::: "memory");

    // ---- phase b: A rows 2-7; MFMA rows 2-3 ----
    if (t + 1 < nt) STG_B(buf ^ 1, 1, t + 1)
    a2[0] = LD8(As, ar + 32, 0);  a2[1] = LD8(As, ar + 32, 1);
    a3[0] = LD8(As, ar + 48, 0);  a3[1] = LD8(As, ar + 48, 1);
    a4[0] = LD8(As, ar + 64, 0);  a4[1] = LD8(As, ar + 64, 1);
    a5[0] = LD8(As, ar + 80, 0);  a5[1] = LD8(As, ar + 80, 1);
    a0[0] = LD8(As, ar + 96, 0);  a0[1] = LD8(As, ar + 96, 1);
    a1[0] = LD8(As, ar + 112, 0); a1[1] = LD8(As, ar + 112, 1);
    asm volatile("s_barrier" ::: "memory");
    __builtin_amdgcn_s_setprio(1);
    MFMA_PAIR(2, a2) MFMA_PAIR(3, a3)
    __builtin_amdgcn_s_setprio(0);
    // all this wave's ds_reads must be complete before next phase's STG_A overwrites As
    asm volatile("s_waitcnt lgkmcnt(0)" ::: "memory");
    asm volatile("s_barrier" ::: "memory");

    // ---- phase c: stage (t+2) A half0 into freed buf; MFMA rows 4-5 ----
    if (t + 2 < nt) STG_A(buf, 0, t + 2)
    __builtin_amdgcn_s_setprio(1);
    MFMA_PAIR(4, a4) MFMA_PAIR(5, a5)
    __builtin_amdgcn_s_setprio(0);
    asm volatile("s_barrier" ::: "memory");

    // ---- phase d: stage (t+2) A half1; MFMA rows 6-7; counted wait ----
    if (t + 2 < nt) STG_A(buf, 1, t + 2)
    __builtin_amdgcn_s_setprio(1);
    MFMA_PAIR(6, a0) MFMA_PAIR(7, a1)
    __builtin_amdgcn_s_setprio(0);
    if (t + 2 < nt)      { asm volatile("s_waitcnt vmcnt(4)" ::: "memory"); }
    else if (t + 1 < nt) { asm volatile("s_waitcnt vmcnt(0)" ::: "memory"); }
    asm volatile("s_barrier" ::: "memory");
  }

  // epilogue: D layout col = lane&15, row = (lane>>4)*4 + r
  const int r0 = by * 256 + wr * 128 + ((lane >> 4) << 2);
  const int cb = bx * 256 + wc * 64;
  if (EPI == 0) {
#pragma unroll
    for (int mi = 0; mi < 8; ++mi)
#pragma unroll
      for (int ni = 0; ni < 4; ++ni)
#pragma unroll
        for (int r = 0; r < 4; ++r)
          C[(size_t)(r0 + mi * 16 + r) * ldc + cb + ni * 16 + fcol] = acc[mi][ni][r];
  } else {
    const int region = cb >> 11;  // 0=q, 1=k, 2=v (uniform per wave)
    if (region < 2) {
      u16* dst = (region == 0) ? q2 : k2;
      const int cbase = cb & 2047;
#pragma unroll
      for (int mi = 0; mi < 8; ++mi)
#pragma unroll
        for (int ni = 0; ni < 4; ++ni) {
          const int cc = cbase + ni * 16 + fcol;
          const float bv = bias[cb + ni * 16 + fcol];
#pragma unroll
          for (int r = 0; r < 4; ++r) {
            float v = acc[mi][ni][r] + bv;
            u16 hi = f32_bf16_rn(v);
            u16 lo = f32_bf16_rn(v - bf16_f32(hi));
            size_t ro = (size_t)(r0 + mi * 16 + r) * 4096;
            dst[ro + cc] = hi;
            dst[ro + 2048 + cc] = lo;
          }
        }
    } else {
      const int vbase = cb - 4096;
#pragma unroll
      for (int mi = 0; mi < 8; ++mi)
#pragma unroll
        for (int ni = 0; ni < 4; ++ni) {
          const int vc = vbase + ni * 16 + fcol;
          const float bv = bias[cb + ni * 16 + fcol];
          ushort4 o;
          o.x = f32_bf16_rn(acc[mi][ni][0] + bv);
          o.y = f32_bf16_rn(acc[mi][ni][1] + bv);
          o.z = f32_bf16_rn(acc[mi][ni][2] + bv);
          o.w = f32_bf16_rn(acc[mi][ni][3] + bv);
          *(ushort4*)&vT[(size_t)vc * 4096 + r0 + mi * 16] = o;
        }
    }
  }
#undef STG_A
#undef STG_B
#undef LD8
}

// ---------------------------------------------------------------------------
// 128x128 NT GEMM (proven round-1 structure) for PV and out-proj.
// CAUSAL==2: Keff = by*128+128. OUTBF: write bf16 instead of f32.
// ---------------------------------------------------------------------------
template<int CAUSAL, bool HAS_BIAS, bool OUTBF>
__global__ __launch_bounds__(256)
void gemm_nt1(const u16* __restrict__ A, const u16* __restrict__ B,
              void* __restrict__ Cv, const float* __restrict__ bias,
              int M, int N, int K) {
  constexpr int BM = 128, BN = 128, BK = 64;
  __shared__ u16 As[BM * BK];
  __shared__ u16 Bs[BN * BK];

  int bx = blockIdx.x, by = blockIdx.y;
  int Keff = (CAUSAL == 2) ? (by * BM + BM) : K;

  int tid = threadIdx.x;
  int wave = tid >> 6, lane = tid & 63;
  int wr = wave >> 1, wc = wave & 1;

  int srow = lane >> 3;
  int scol = ((lane & 7) ^ srow) << 3;
  const u16* Ag = A + (size_t)(by * BM + wave * 8 + srow) * K + scol;
  const u16* Bg = B + (size_t)(bx * BN + wave * 8 + srow) * K + scol;
  u16* AsW = As + wave * 8 * BK;
  u16* BsW = Bs + wave * 8 * BK;

  f32x4 zero = {0.0f, 0.0f, 0.0f, 0.0f};
  f32x4 acc[4][4];
#pragma unroll
  for (int i = 0; i < 4; ++i)
#pragma unroll
    for (int j = 0; j < 4; ++j) acc[i][j] = zero;

  for (int k0 = 0; k0 < Keff; k0 += BK) {
#pragma unroll
    for (int it = 0; it < 4; ++it) {
      async16(Ag + (size_t)it * 32 * K + k0, AsW + it * 32 * BK);
      async16(Bg + (size_t)it * 32 * K + k0, BsW + it * 32 * BK);
    }
    __syncthreads();

#pragma unroll
    for (int kk = 0; kk < 2; ++kk) {
      bf16x8 af[4], bb[4];
      int col = lane & 15;
      int sl = kk * 4 + (lane >> 4);
#pragma unroll
      for (int mi = 0; mi < 4; ++mi) {
        int row = wr * 64 + mi * 16 + col;
        af[mi] = *(const bf16x8*)&As[row * BK + ((sl ^ (row & 7)) << 3)];
      }
#pragma unroll
      for (int ni = 0; ni < 4; ++ni) {
        int row = wc * 64 + ni * 16 + col;
        bb[ni] = *(const bf16x8*)&Bs[row * BK + ((sl ^ (row & 7)) << 3)];
      }
#pragma unroll
      for (int mi = 0; mi < 4; ++mi)
#pragma unroll
        for (int ni = 0; ni < 4; ++ni)
          acc[mi][ni] = __builtin_amdgcn_mfma_f32_16x16x32_bf16(
              af[mi], bb[ni], acc[mi][ni], 0, 0, 0);
    }
    __syncthreads();
  }

  int r0 = by * BM + wr * 64 + ((lane >> 4) << 2);
  int c0 = bx * BN + wc * 64 + (lane & 15);
#pragma unroll
  for (int mi = 0; mi < 4; ++mi)
#pragma unroll
    for (int ni = 0; ni < 4; ++ni) {
      int cc = c0 + ni * 16;
      float bv = HAS_BIAS ? bias[cc] : 0.0f;
#pragma unroll
      for (int r = 0; r < 4; ++r) {
        float v = acc[mi][ni][r] + bv;
        size_t idx = (size_t)(r0 + mi * 16 + r) * N + cc;
        if (OUTBF) ((u16*)Cv)[idx] = f32_bf16_rn(v);
        else       ((float*)Cv)[idx] = v;
      }
    }
}

// ---------------------------------------------------------------------------
extern "C" void kernel_launch(void* const* d_in, const int* in_sizes, int n_in,
                              void* d_out, int out_size, void* d_ws, size_t ws_size,
                              hipStream_t stream) {
  (void)in_sizes; (void)n_in; (void)out_size; (void)ws_size;
  const float* x     = (const float*)d_in[0];  // [4096][2048]
  const float* Wqkv  = (const float*)d_in[1];  // [6144][2048]
  const float* bqkv  = (const float*)d_in[2];  // [6144]
  const float* Wproj = (const float*)d_in[3];  // [2048][2048]
  const float* bproj = (const float*)d_in[4];  // [2048]
  float* out = (float*)d_out;                  // [4096][2048]

  char* w = (char*)d_ws;
  u16*   x2   = (u16*)w;                       // [4096][4096] bf16 [h|l]      @0       33.5MB
  u16*   W2   = (u16*)(w + 33554432);          // [6144][4096] bf16 [h|l]               50.3MB
  u16*   q2   = (u16*)(w + 83886080);          // [4096][4096] bf16 [h|l]               33.5MB
  u16*   k2   = (u16*)(w + 117440512);         // [4096][4096] bf16 [h|l]               33.5MB
  u16*   vT   = (u16*)(w + 150994944);         // [2048][4096] bf16 (v^T)               16.8MB
  float* Smat = (float*)w;                     // [4096][4096] f32  (x2/W2 dead)        67.1MB
  u16*   P    = (u16*)(w + 67108864);          // [4096][4096] bf16 (dead W2/q2 region) 33.5MB
  u16*   ao   = (u16*)(w + 100663296);         // [4096][2048] bf16 (dead q2 tail)      16.8MB
  u16*   Wp   = (u16*)(w + 117440512);         // [2048][2048] bf16 (dead k2)            8.4MB

  // 1) hi/lo splits of x and Wqkv
  split2<<<2048, 256, 0, stream>>>(x,    x2, (size_t)4096 * 2048);
  split2<<<2048, 256, 0, stream>>>(Wqkv, W2, (size_t)6144 * 2048);

  // 2) QKV projection (3-term split via K-remap), epilogue writes q2/k2/vT + bias
  gemm_nt2<1, 1, 2, 0><<<dim3(24, 16), 512, 0, stream>>>(
      x2, 4096, W2, 4096, nullptr, 0, q2, k2, vT, bqkv, 6144);

  // 3) S = k @ q^T (causal tiles, 3-term split), f32 out
  gemm_nt2<0, 1, 2, 1><<<dim3(16, 16), 512, 0, stream>>>(
      k2, 4096, q2, 4096, Smat, 4096, nullptr, nullptr, nullptr, nullptr, 6144);

  // 4) softmax rows -> P (bf16, zero-padded to 128 boundary)
  softmax_causal<<<4096, 256, 0, stream>>>(Smat, P, 4096);

  // 5) attn = P @ v (K-limited per 128-row block), bf16 out
  gemm_nt1<2, false, true><<<dim3(16, 32), 256, 0, stream>>>(
      P, vT, (void*)ao, nullptr, 4096, 2048, 4096);

  // 6) out = attn @ Wproj^T + bproj
  cast_bf16_k<<<1024, 256, 0, stream>>>(Wproj, Wp, 2048 * 2048 / 4);
  gemm_nt1<0, true, false><<<dim3(16, 32), 256, 0, stream>>>(
      ao, Wp, (void*)out, bproj, 4096, 2048, 2048);
}

// Round 3
// 750.981 us; speedup vs baseline: 1.1115x; 1.0090x over previous
//
#include <hip/hip_runtime.h>
#include <stdint.h>

typedef unsigned short u16;
typedef __bf16 bf16x8 __attribute__((ext_vector_type(8)));
typedef float f32x4 __attribute__((ext_vector_type(4)));

__device__ __forceinline__ u16 f32_bf16_rn(float f) {
  uint32_t u = __float_as_uint(f);
  uint32_t r = (u + 0x7FFFu + ((u >> 16) & 1u)) >> 16;
  return (u16)r;
}
__device__ __forceinline__ float bf16_f32(u16 h) {
  return __uint_as_float(((uint32_t)h) << 16);
}

// async global->LDS, 16B per lane. LDS dest = wave-uniform base + lane*16.
__device__ __forceinline__ void async16(const u16* g, u16* l) {
  __builtin_amdgcn_global_load_lds(
      (__attribute__((address_space(1))) void*)(g),
      (__attribute__((address_space(3))) void*)(l), 16, 0, 0);
}

// f32 [R][2048] -> bf16 [R][4096] as [hi | lo]
__global__ __launch_bounds__(256)
void split2(const float* __restrict__ in, u16* __restrict__ out, size_t total) {
  size_t stride = (size_t)gridDim.x * blockDim.x;
  for (size_t idx = (size_t)blockIdx.x * blockDim.x + threadIdx.x; idx < total; idx += stride) {
    int r = (int)(idx >> 11);
    int c = (int)(idx & 2047);
    float f = in[idx];
    u16 hi = f32_bf16_rn(f);
    u16 lo = f32_bf16_rn(f - bf16_f32(hi));
    out[(size_t)r * 4096 + c] = hi;
    out[(size_t)r * 4096 + 2048 + c] = lo;
  }
}

__global__ __launch_bounds__(256)
void cast_bf16_k(const float* __restrict__ in, u16* __restrict__ out, int n4) {
  int stride = gridDim.x * blockDim.x;
  for (int i = blockIdx.x * blockDim.x + threadIdx.x; i < n4; i += stride) {
    float4 f = ((const float4*)in)[i];
    ushort4 o;
    o.x = f32_bf16_rn(f.x); o.y = f32_bf16_rn(f.y);
    o.z = f32_bf16_rn(f.z); o.w = f32_bf16_rn(f.w);
    ((ushort4*)out)[i] = o;
  }
}

// ---------------------------------------------------------------------------
// causal row softmax: S f32 [4096][4096] -> P bf16, row i valid cols 0..i,
// zero-fill up to next 128 boundary (PV gemm K-limits there).
// ---------------------------------------------------------------------------
__device__ __forceinline__ float waveMax(float v) {
#pragma unroll
  for (int o = 32; o > 0; o >>= 1) v = fmaxf(v, __shfl_xor(v, o));
  return v;
}
__device__ __forceinline__ float waveSum(float v) {
#pragma unroll
  for (int o = 32; o > 0; o >>= 1) v += __shfl_xor(v, o);
  return v;
}

__global__ __launch_bounds__(256)
void softmax_causal(const float* __restrict__ S, u16* __restrict__ P, int L) {
  int row = blockIdx.x;
  int tid = threadIdx.x;
  int wave = tid >> 6, lane = tid & 63;
  int n = row + 1;
  int pad = ((row >> 7) + 1) << 7;
  const float* s = S + (size_t)row * L;
  __shared__ float sred[8];

  float m = -3.4e38f;
  for (int j = tid; j < n; j += 256) m = fmaxf(m, s[j]);
  m = waveMax(m);
  if (lane == 0) sred[wave] = m;
  __syncthreads();
  m = fmaxf(fmaxf(sred[0], sred[1]), fmaxf(sred[2], sred[3]));

  float sum = 0.0f;
  for (int j = tid; j < n; j += 256) sum += __expf(s[j] - m);
  sum = waveSum(sum);
  if (lane == 0) sred[4 + wave] = sum;
  __syncthreads();
  sum = sred[4] + sred[5] + sred[6] + sred[7];
  float inv = 1.0f / sum;

  u16* p = P + (size_t)row * L;
  for (int j = tid; j < pad; j += 256) {
    float v = (j < n) ? __expf(s[j] - m) * inv : 0.0f;
    p[j] = f32_bf16_rn(v);
  }
}

// ---------------------------------------------------------------------------
// K-remap for the 3-term bf16 split GEMM over physical [hi|lo] storage:
// mode 0: identity. mode 1: [h|l|h] (A side). mode 2: [h|h|l] (B side).
// K-tile t (BK=64), D=2048, logical K=6144, physical ld 4096.
// ---------------------------------------------------------------------------
__device__ __forceinline__ int kmap(int mode, int t) {
  if (mode == 1) return (t < 32) ? t * 64 : (t < 64) ? 2048 + (t - 32) * 64 : (t - 64) * 64;
  if (mode == 2) return (t < 32) ? t * 64 : (t < 64) ? (t - 32) * 64 : 2048 + (t - 64) * 64;
  return t * 64;
}

// ---------------------------------------------------------------------------
// 256x256 8-wave NT GEMM, faithful 8-phase template port (m201 structure).
// BK=64, dbuf LDS split into row-halves: Asm/Bsm[buf][half][128*64].
// Per iteration: 2 K-tiles (T -> buf0, T+1 -> buf1), 8 phases, one half-tile
// staged per phase, vmcnt(4) at phases 4/8, sched_barrier-pinned MFMA.
// EPI 0: C f32 (ldc).  EPI 1: QKV epilogue -> q2 [h|l], k2 [h|l], vT, +bias.
// CAUSAL 1: skip tiles with bx > by (M==N grid).
// ---------------------------------------------------------------------------
#define MFMA(a, b, c) __builtin_amdgcn_mfma_f32_16x16x32_bf16((a), (b), (c), 0, 0, 0)

#define STG(gbase, ld, kc, dstbase) { \
  const u16* g_ = (gbase) + (size_t)(w * 8 + srow) * (ld) + (kc) + scol; \
  u16* l_ = (dstbase) + w * 8 * 64; \
  async16(g_, l_); \
  async16(g_ + (size_t)64 * (ld), l_ + 64 * 64); }

#define STG_A(bufi, half, tt) STG(Agb + (size_t)(half) * 128 * lda, lda, kmap(AMAP, (tt)), &Asm[bufi][half][0])
#define STG_B(bufi, half, tt) STG(Bgb + (size_t)(half) * 128 * ldb, ldb, kmap(BMAP, (tt)), &Bsm[bufi][half][0])

#define LD8H(Hb, lr, ks) (*(const bf16x8*)&(Hb)[((lr) + fcol) * 64 + ((((ks) * 4 + fks) ^ rx) << 3)])

#define PHASE(Q, BUFI, STAGE_STMT, VMSTMT) { \
  const u16* Ah = &Asm[BUFI][wr][0]; \
  const u16* Bh = &Bsm[BUFI][wc >> 1][0]; \
  STAGE_STMT; \
  if ((Q) == 0) { \
    _Pragma("unroll") \
    for (int ni = 0; ni < 4; ++ni) { \
      bfr[ni][0] = LD8H(Bh, (wc & 1) * 64 + ni * 16, 0); \
      bfr[ni][1] = LD8H(Bh, (wc & 1) * 64 + ni * 16, 1); \
    } \
  } \
  af[0][0] = LD8H(Ah, (Q) * 32, 0);      af[0][1] = LD8H(Ah, (Q) * 32, 1); \
  af[1][0] = LD8H(Ah, (Q) * 32 + 16, 0); af[1][1] = LD8H(Ah, (Q) * 32 + 16, 1); \
  asm volatile("s_barrier" ::: "memory"); \
  __builtin_amdgcn_sched_barrier(0); \
  __builtin_amdgcn_s_setprio(1); \
  _Pragma("unroll") \
  for (int ni = 0; ni < 4; ++ni) { \
    acc[(Q) * 2][ni]     = MFMA(af[0][0], bfr[ni][0], acc[(Q) * 2][ni]); \
    acc[(Q) * 2][ni]     = MFMA(af[0][1], bfr[ni][1], acc[(Q) * 2][ni]); \
    acc[(Q) * 2 + 1][ni] = MFMA(af[1][0], bfr[ni][0], acc[(Q) * 2 + 1][ni]); \
    acc[(Q) * 2 + 1][ni] = MFMA(af[1][1], bfr[ni][1], acc[(Q) * 2 + 1][ni]); \
  } \
  __builtin_amdgcn_s_setprio(0); \
  __builtin_amdgcn_sched_barrier(0); \
  VMSTMT; \
  asm volatile("s_barrier" ::: "memory"); }

template<int EPI, int AMAP, int BMAP, int CAUSAL>
__global__ __launch_bounds__(512, 2)
void gemm_nt2(const u16* __restrict__ A, int lda, const u16* __restrict__ B, int ldb,
              float* __restrict__ C, int ldc,
              u16* __restrict__ q2, u16* __restrict__ k2, u16* __restrict__ vT,
              const float* __restrict__ bias, int K) {
  __shared__ u16 Asm[2][2][128 * 64];
  __shared__ u16 Bsm[2][2][128 * 64];
  const int bx = blockIdx.x, by = blockIdx.y;
  if (CAUSAL == 1 && bx > by) return;
  const int nt = K / 64;   // even, >= 4 in all uses

  const int tid = threadIdx.x;
  const int w = tid >> 6, lane = tid & 63;
  const int wr = w >> 2, wc = w & 3;
  const int srow = lane >> 3;
  const int scol = ((lane & 7) ^ srow) << 3;   // pre-swizzled source column
  const u16* Agb = A + (size_t)(by * 256) * lda;
  const u16* Bgb = B + (size_t)(bx * 256) * ldb;

  const int fcol = lane & 15;
  const int fks = lane >> 4;
  const int rx = fcol & 7;

  f32x4 acc[8][4];
#pragma unroll
  for (int i = 0; i < 8; ++i)
#pragma unroll
    for (int j = 0; j < 4; ++j) acc[i][j] = (f32x4){0.f, 0.f, 0.f, 0.f};
  bf16x8 bfr[4][2];
  bf16x8 af[2][2];

  // prologue: tile0 A+B (buf0), tile1 B (buf1): 12 loads/thread, keep 4 in flight
  STG_A(0, 0, 0) STG_A(0, 1, 0) STG_B(0, 0, 0) STG_B(0, 1, 0)
  STG_B(1, 0, 1) STG_B(1, 1, 1)
  asm volatile("s_waitcnt vmcnt(4)" ::: "memory");
  asm volatile("s_barrier" ::: "memory");

  for (int T = 0; T < nt; T += 2) {
    // phases 1-4: K-tile T (buf0)
    PHASE(0, 0, if (T + 1 < nt) STG_A(1, 0, T + 1), )
    PHASE(1, 0, if (T + 1 < nt) STG_A(1, 1, T + 1), )
    PHASE(2, 0, if (T + 2 < nt) STG_B(0, 0, T + 2), )
    PHASE(3, 0, if (T + 2 < nt) STG_B(0, 1, T + 2),
          if (T + 2 < nt) { asm volatile("s_waitcnt vmcnt(4)" ::: "memory"); }
          else { asm volatile("s_waitcnt vmcnt(0)" ::: "memory"); })
    // phases 5-8: K-tile T+1 (buf1)
    PHASE(0, 1, if (T + 2 < nt) STG_A(0, 0, T + 2), )
    PHASE(1, 1, if (T + 2 < nt) STG_A(0, 1, T + 2), )
    PHASE(2, 1, if (T + 3 < nt) STG_B(1, 0, T + 3), )
    PHASE(3, 1, if (T + 3 < nt) STG_B(1, 1, T + 3),
          if (T + 3 < nt) { asm volatile("s_waitcnt vmcnt(4)" ::: "memory"); }
          else { asm volatile("s_waitcnt vmcnt(0)" ::: "memory"); })
  }

  // epilogue: D layout col = lane&15, row = (lane>>4)*4 + r ; acc[m] rows m*16
  const int r0 = by * 256 + wr * 128 + ((lane >> 4) << 2);
  const int cb = bx * 256 + wc * 64;
  if (EPI == 0) {
#pragma unroll
    for (int mi = 0; mi < 8; ++mi)
#pragma unroll
      for (int ni = 0; ni < 4; ++ni)
#pragma unroll
        for (int r = 0; r < 4; ++r)
          C[(size_t)(r0 + mi * 16 + r) * ldc + cb + ni * 16 + fcol] = acc[mi][ni][r];
  } else {
    const int region = cb >> 11;  // 0=q, 1=k, 2=v (uniform per wave)
    if (region < 2) {
      u16* dst = (region == 0) ? q2 : k2;
      const int cbase = cb & 2047;
#pragma unroll
      for (int mi = 0; mi < 8; ++mi)
#pragma unroll
        for (int ni = 0; ni < 4; ++ni) {
          const int cc = cbase + ni * 16 + fcol;
          const float bv = bias[cb + ni * 16 + fcol];
#pragma unroll
          for (int r = 0; r < 4; ++r) {
            float v = acc[mi][ni][r] + bv;
            u16 hi = f32_bf16_rn(v);
            u16 lo = f32_bf16_rn(v - bf16_f32(hi));
            size_t ro = (size_t)(r0 + mi * 16 + r) * 4096;
            dst[ro + cc] = hi;
            dst[ro + 2048 + cc] = lo;
          }
        }
    } else {
      const int vbase = cb - 4096;
#pragma unroll
      for (int mi = 0; mi < 8; ++mi)
#pragma unroll
        for (int ni = 0; ni < 4; ++ni) {
          const int vc = vbase + ni * 16 + fcol;
          const float bv = bias[cb + ni * 16 + fcol];
          ushort4 o;
          o.x = f32_bf16_rn(acc[mi][ni][0] + bv);
          o.y = f32_bf16_rn(acc[mi][ni][1] + bv);
          o.z = f32_bf16_rn(acc[mi][ni][2] + bv);
          o.w = f32_bf16_rn(acc[mi][ni][3] + bv);
          *(ushort4*)&vT[(size_t)vc * 4096 + r0 + mi * 16] = o;
        }
    }
  }
}

// ---------------------------------------------------------------------------
// 128x128 NT GEMM (proven round-1 structure) for PV and out-proj.
// CAUSAL==2: Keff = by*128+128. OUTBF: write bf16 instead of f32.
// ---------------------------------------------------------------------------
template<int CAUSAL, bool HAS_BIAS, bool OUTBF>
__global__ __launch_bounds__(256)
void gemm_nt1(const u16* __restrict__ A, const u16* __restrict__ B,
              void* __restrict__ Cv, const float* __restrict__ bias,
              int M, int N, int K) {
  constexpr int BM = 128, BN = 128, BK = 64;
  __shared__ u16 As[BM * BK];
  __shared__ u16 Bs[BN * BK];

  int bx = blockIdx.x, by = blockIdx.y;
  int Keff = (CAUSAL == 2) ? (by * BM + BM) : K;

  int tid = threadIdx.x;
  int wave = tid >> 6, lane = tid & 63;
  int wr = wave >> 1, wc = wave & 1;

  int srow = lane >> 3;
  int scol = ((lane & 7) ^ srow) << 3;
  const u16* Ag = A + (size_t)(by * BM + wave * 8 + srow) * K + scol;
  const u16* Bg = B + (size_t)(bx * BN + wave * 8 + srow) * K + scol;
  u16* AsW = As + wave * 8 * BK;
  u16* BsW = Bs + wave * 8 * BK;

  f32x4 zero = {0.0f, 0.0f, 0.0f, 0.0f};
  f32x4 acc[4][4];
#pragma unroll
  for (int i = 0; i < 4; ++i)
#pragma unroll
    for (int j = 0; j < 4; ++j) acc[i][j] = zero;

  for (int k0 = 0; k0 < Keff; k0 += BK) {
#pragma unroll
    for (int it = 0; it < 4; ++it) {
      async16(Ag + (size_t)it * 32 * K + k0, AsW + it * 32 * BK);
      async16(Bg + (size_t)it * 32 * K + k0, BsW + it * 32 * BK);
    }
    __syncthreads();

#pragma unroll
    for (int kk = 0; kk < 2; ++kk) {
      bf16x8 af[4], bb[4];
      int col = lane & 15;
      int sl = kk * 4 + (lane >> 4);
#pragma unroll
      for (int mi = 0; mi < 4; ++mi) {
        int row = wr * 64 + mi * 16 + col;
        af[mi] = *(const bf16x8*)&As[row * BK + ((sl ^ (row & 7)) << 3)];
      }
#pragma unroll
      for (int ni = 0; ni < 4; ++ni) {
        int row = wc * 64 + ni * 16 + col;
        bb[ni] = *(const bf16x8*)&Bs[row * BK + ((sl ^ (row & 7)) << 3)];
      }
#pragma unroll
      for (int mi = 0; mi < 4; ++mi)
#pragma unroll
        for (int ni = 0; ni < 4; ++ni)
          acc[mi][ni] = __builtin_amdgcn_mfma_f32_16x16x32_bf16(
              af[mi], bb[ni], acc[mi][ni], 0, 0, 0);
    }
    __syncthreads();
  }

  int r0 = by * BM + wr * 64 + ((lane >> 4) << 2);
  int c0 = bx * BN + wc * 64 + (lane & 15);
#pragma unroll
  for (int mi = 0; mi < 4; ++mi)
#pragma unroll
    for (int ni = 0; ni < 4; ++ni) {
      int cc = c0 + ni * 16;
      float bv = HAS_BIAS ? bias[cc] : 0.0f;
#pragma unroll
      for (int r = 0; r < 4; ++r) {
        float v = acc[mi][ni][r] + bv;
        size_t idx = (size_t)(r0 + mi * 16 + r) * N + cc;
        if (OUTBF) ((u16*)Cv)[idx] = f32_bf16_rn(v);
        else       ((float*)Cv)[idx] = v;
      }
    }
}

// ---------------------------------------------------------------------------
extern "C" void kernel_launch(void* const* d_in, const int* in_sizes, int n_in,
                              void* d_out, int out_size, void* d_ws, size_t ws_size,
                              hipStream_t stream) {
  (void)in_sizes; (void)n_in; (void)out_size; (void)ws_size;
  const float* x     = (const float*)d_in[0];  // [4096][2048]
  const float* Wqkv  = (const float*)d_in[1];  // [6144][2048]
  const float* bqkv  = (const float*)d_in[2];  // [6144]
  const float* Wproj = (const float*)d_in[3];  // [2048][2048]
  const float* bproj = (const float*)d_in[4];  // [2048]
  float* out = (float*)d_out;                  // [4096][2048]

  char* w = (char*)d_ws;
  u16*   x2   = (u16*)w;                       // [4096][4096] bf16 [h|l]      @0       33.5MB
  u16*   W2   = (u16*)(w + 33554432);          // [6144][4096] bf16 [h|l]               50.3MB
  u16*   q2   = (u16*)(w + 83886080);          // [4096][4096] bf16 [h|l]               33.5MB
  u16*   k2   = (u16*)(w + 117440512);         // [4096][4096] bf16 [h|l]               33.5MB
  u16*   vT   = (u16*)(w + 150994944);         // [2048][4096] bf16 (v^T)               16.8MB
  float* Smat = (float*)w;                     // [4096][4096] f32  (x2/W2 dead)        67.1MB
  u16*   P    = (u16*)(w + 67108864);          // [4096][4096] bf16 (dead W2/q2 region) 33.5MB
  u16*   ao   = (u16*)(w + 100663296);         // [4096][2048] bf16 (dead q2 tail)      16.8MB
  u16*   Wp   = (u16*)(w + 117440512);         // [2048][2048] bf16 (dead k2)            8.4MB

  // 1) hi/lo splits of x and Wqkv
  split2<<<2048, 256, 0, stream>>>(x,    x2, (size_t)4096 * 2048);
  split2<<<2048, 256, 0, stream>>>(Wqkv, W2, (size_t)6144 * 2048);

  // 2) QKV projection (3-term split via K-remap), epilogue writes q2/k2/vT + bias
  gemm_nt2<1, 1, 2, 0><<<dim3(24, 16), 512, 0, stream>>>(
      x2, 4096, W2, 4096, nullptr, 0, q2, k2, vT, bqkv, 6144);

  // 3) S = k @ q^T (causal tiles, 3-term split), f32 out
  gemm_nt2<0, 1, 2, 1><<<dim3(16, 16), 512, 0, stream>>>(
      k2, 4096, q2, 4096, Smat, 4096, nullptr, nullptr, nullptr, nullptr, 6144);

  // 4) softmax rows -> P (bf16, zero-padded to 128 boundary)
  softmax_causal<<<4096, 256, 0, stream>>>(Smat, P, 4096);

  // 5) attn = P @ v (K-limited per 128-row block), bf16 out
  gemm_nt1<2, false, true><<<dim3(16, 32), 256, 0, stream>>>(
      P, vT, (void*)ao, nullptr, 4096, 2048, 4096);

  // 6) out = attn @ Wproj^T + bproj
  cast_bf16_k<<<1024, 256, 0, stream>>>(Wproj, Wp, 2048 * 2048 / 4);
  gemm_nt1<0, true, false><<<dim3(16, 32), 256, 0, stream>>>(
      ao, Wp, (void*)out, bproj, 4096, 2048, 2048);
}

// Round 4
// 700.960 us; speedup vs baseline: 1.1908x; 1.0714x over previous
//
#include <hip/hip_runtime.h>
#include <stdint.h>

typedef unsigned short u16;
typedef __bf16 bf16x8 __attribute__((ext_vector_type(8)));
typedef float f32x4 __attribute__((ext_vector_type(4)));

__device__ __forceinline__ u16 f32_bf16_rn(float f) {
  uint32_t u = __float_as_uint(f);
  uint32_t r = (u + 0x7FFFu + ((u >> 16) & 1u)) >> 16;
  return (u16)r;
}
__device__ __forceinline__ float bf16_f32(u16 h) {
  return __uint_as_float(((uint32_t)h) << 16);
}

// async global->LDS, 16B per lane. LDS dest = wave-uniform base + lane*16.
__device__ __forceinline__ void async16(const u16* g, u16* l) {
  __builtin_amdgcn_global_load_lds(
      (__attribute__((address_space(1))) void*)(g),
      (__attribute__((address_space(3))) void*)(l), 16, 0, 0);
}

// f32 [R][2048] -> bf16 [R][4096] as [hi | lo]
__global__ __launch_bounds__(256)
void split2(const float* __restrict__ in, u16* __restrict__ out, size_t total) {
  size_t stride = (size_t)gridDim.x * blockDim.x;
  for (size_t idx = (size_t)blockIdx.x * blockDim.x + threadIdx.x; idx < total; idx += stride) {
    int r = (int)(idx >> 11);
    int c = (int)(idx & 2047);
    float f = in[idx];
    u16 hi = f32_bf16_rn(f);
    u16 lo = f32_bf16_rn(f - bf16_f32(hi));
    out[(size_t)r * 4096 + c] = hi;
    out[(size_t)r * 4096 + 2048 + c] = lo;
  }
}

// plain f32 -> bf16 cast, 4-wide
__global__ __launch_bounds__(256)
void cast_bf16_k(const float* __restrict__ in, u16* __restrict__ out, int n4) {
  int stride = gridDim.x * blockDim.x;
  for (int i = blockIdx.x * blockDim.x + threadIdx.x; i < n4; i += stride) {
    float4 f = ((const float4*)in)[i];
    ushort4 o;
    o.x = f32_bf16_rn(f.x); o.y = f32_bf16_rn(f.y);
    o.z = f32_bf16_rn(f.z); o.w = f32_bf16_rn(f.w);
    ((ushort4*)out)[i] = o;
  }
}

// ---------------------------------------------------------------------------
// 2-pass causal row softmax: S f32 [4096][4096] -> P bf16 (UNSCALED exp),
// inv[row] = 1/sum. Row i valid cols 0..i, zero-fill to next 128 boundary.
// PV epilogue multiplies output row by inv[row].
// ---------------------------------------------------------------------------
__device__ __forceinline__ float waveMax(float v) {
#pragma unroll
  for (int o = 32; o > 0; o >>= 1) v = fmaxf(v, __shfl_xor(v, o));
  return v;
}
__device__ __forceinline__ float waveSum(float v) {
#pragma unroll
  for (int o = 32; o > 0; o >>= 1) v += __shfl_xor(v, o);
  return v;
}

__global__ __launch_bounds__(256)
void softmax_causal(const float* __restrict__ S, u16* __restrict__ P,
                    float* __restrict__ inv, int L) {
  int row = blockIdx.x;
  int tid = threadIdx.x;
  int wave = tid >> 6, lane = tid & 63;
  int n = row + 1;
  int pad = ((row >> 7) + 1) << 7;
  const float* s = S + (size_t)row * L;
  __shared__ float sred[8];

  float m = -3.4e38f;
  for (int j = tid; j < n; j += 256) m = fmaxf(m, s[j]);
  m = waveMax(m);
  if (lane == 0) sred[wave] = m;
  __syncthreads();
  m = fmaxf(fmaxf(sred[0], sred[1]), fmaxf(sred[2], sred[3]));

  u16* p = P + (size_t)row * L;
  float sum = 0.0f;
  for (int j = tid; j < pad; j += 256) {
    float e = (j < n) ? __expf(s[j] - m) : 0.0f;
    p[j] = f32_bf16_rn(e);
    sum += e;
  }
  sum = waveSum(sum);
  if (lane == 0) sred[4 + wave] = sum;
  __syncthreads();
  if (tid == 0) inv[row] = 1.0f / (sred[4] + sred[5] + sred[6] + sred[7]);
}

// ---------------------------------------------------------------------------
// K-remap for the 3-term bf16 split GEMM over physical [hi|lo] storage:
// mode 0: identity. mode 1: [h|l|h] (A side). mode 2: [h|h|l] (B side).
// ---------------------------------------------------------------------------
__device__ __forceinline__ int kmap(int mode, int t) {
  if (mode == 1) return (t < 32) ? t * 64 : (t < 64) ? 2048 + (t - 32) * 64 : (t - 64) * 64;
  if (mode == 2) return (t < 32) ? t * 64 : (t < 64) ? (t - 32) * 64 : 2048 + (t - 64) * 64;
  return t * 64;
}

// ---------------------------------------------------------------------------
// Unified 128x128 NT GEMM (proven round-1 structure), BK=64, 4 waves,
// 4x4 frags of mfma_f32_16x16x32_bf16, XOR-swizzled LDS via pre-swizzled
// global source + swizzled ds_read.
//   C[M][N] = A[M][K_logical] * B[N][K_logical]^T  (K via kmap over lda/ldb)
// CAUSAL 1: skip blocks above diagonal (S). CAUSAL 2: Keff=by*128+128 (PV).
// EPI 0: f32 C (ldc) [+bias]. EPI 1: qk hi/lo split out (+bias).
// EPI 2: vT transposed bf16 (+bias). EPI 3: bf16 row-major, xrow-scale inv[].
// ---------------------------------------------------------------------------
template<int EPI, int AMAP, int BMAP, int CAUSAL, bool HAS_BIAS>
__global__ __launch_bounds__(256)
void gemm_u(const u16* __restrict__ A, int lda, const u16* __restrict__ B, int ldb,
            float* __restrict__ Cf, u16* __restrict__ o16, int ldc,
            u16* __restrict__ eq, u16* __restrict__ ek,
            const float* __restrict__ bias, const float* __restrict__ inv, int K) {
  constexpr int BM = 128, BN = 128, BK = 64;
  __shared__ u16 As[BM * BK];
  __shared__ u16 Bs[BN * BK];

  int bx = blockIdx.x, by = blockIdx.y;
  if (CAUSAL == 1 && bx > by) return;
  int Keff = (CAUSAL == 2) ? (by * BM + BM) : K;

  int tid = threadIdx.x;
  int wave = tid >> 6, lane = tid & 63;
  int wr = wave >> 1, wc = wave & 1;

  int srow = lane >> 3;
  int scol = ((lane & 7) ^ srow) << 3;
  const u16* Ag = A + (size_t)(by * BM + wave * 8 + srow) * lda + scol;
  const u16* Bg = B + (size_t)(bx * BN + wave * 8 + srow) * ldb + scol;
  u16* AsW = As + wave * 8 * BK;
  u16* BsW = Bs + wave * 8 * BK;

  f32x4 zero = {0.0f, 0.0f, 0.0f, 0.0f};
  f32x4 acc[4][4];
#pragma unroll
  for (int i = 0; i < 4; ++i)
#pragma unroll
    for (int j = 0; j < 4; ++j) acc[i][j] = zero;

  for (int k0 = 0; k0 < Keff; k0 += BK) {
    const int t = k0 >> 6;
    const int kca = kmap(AMAP, t);
    const int kcb = kmap(BMAP, t);
#pragma unroll
    for (int it = 0; it < 4; ++it) {
      async16(Ag + (size_t)it * 32 * lda + kca, AsW + it * 32 * BK);
      async16(Bg + (size_t)it * 32 * ldb + kcb, BsW + it * 32 * BK);
    }
    __syncthreads();

#pragma unroll
    for (int kk = 0; kk < 2; ++kk) {
      bf16x8 af[4], bb[4];
      int col = lane & 15;
      int sl = kk * 4 + (lane >> 4);
#pragma unroll
      for (int mi = 0; mi < 4; ++mi) {
        int row = wr * 64 + mi * 16 + col;
        af[mi] = *(const bf16x8*)&As[row * BK + ((sl ^ (row & 7)) << 3)];
      }
#pragma unroll
      for (int ni = 0; ni < 4; ++ni) {
        int row = wc * 64 + ni * 16 + col;
        bb[ni] = *(const bf16x8*)&Bs[row * BK + ((sl ^ (row & 7)) << 3)];
      }
#pragma unroll
      for (int mi = 0; mi < 4; ++mi)
#pragma unroll
        for (int ni = 0; ni < 4; ++ni)
          acc[mi][ni] = __builtin_amdgcn_mfma_f32_16x16x32_bf16(
              af[mi], bb[ni], acc[mi][ni], 0, 0, 0);
    }
    __syncthreads();
  }

  // epilogue: D layout col = lane&15, row = (lane>>4)*4 + r
  const int fcol = lane & 15;
  const int r0 = by * BM + wr * 64 + ((lane >> 4) << 2);

  if (EPI == 0) {
#pragma unroll
    for (int mi = 0; mi < 4; ++mi)
#pragma unroll
      for (int ni = 0; ni < 4; ++ni) {
        int cc = bx * BN + wc * 64 + ni * 16 + fcol;
        float bv = HAS_BIAS ? bias[cc] : 0.0f;
#pragma unroll
        for (int r = 0; r < 4; ++r)
          Cf[(size_t)(r0 + mi * 16 + r) * ldc + cc] = acc[mi][ni][r] + bv;
      }
  } else if (EPI == 1) {
    // qk epilogue: global col in [0,4096); <2048 -> q2, else k2; hi/lo split
    const int colb = bx * BN + wc * 64;       // uniform per wave
    u16* dst = (colb < 2048) ? eq : ek;
    const int cbase = colb & 2047;
#pragma unroll
    for (int mi = 0; mi < 4; ++mi)
#pragma unroll
      for (int ni = 0; ni < 4; ++ni) {
        const int cc = cbase + ni * 16 + fcol;
        const float bv = HAS_BIAS ? bias[colb + ni * 16 + fcol] : 0.0f;
#pragma unroll
        for (int r = 0; r < 4; ++r) {
          float v = acc[mi][ni][r] + bv;
          u16 hi = f32_bf16_rn(v);
          u16 lo = f32_bf16_rn(v - bf16_f32(hi));
          size_t ro = (size_t)(r0 + mi * 16 + r) * 4096;
          dst[ro + cc] = hi;
          dst[ro + 2048 + cc] = lo;
        }
      }
  } else if (EPI == 2) {
    // vT epilogue: out[vc][seq] bf16, vc in [0,2048)
#pragma unroll
    for (int mi = 0; mi < 4; ++mi)
#pragma unroll
      for (int ni = 0; ni < 4; ++ni) {
        const int vc = bx * BN + wc * 64 + ni * 16 + fcol;
        const float bv = HAS_BIAS ? bias[vc] : 0.0f;
        ushort4 o;
        o.x = f32_bf16_rn(acc[mi][ni][0] + bv);
        o.y = f32_bf16_rn(acc[mi][ni][1] + bv);
        o.z = f32_bf16_rn(acc[mi][ni][2] + bv);
        o.w = f32_bf16_rn(acc[mi][ni][3] + bv);
        *(ushort4*)&o16[(size_t)vc * 4096 + r0 + mi * 16] = o;
      }
  } else {
    // EPI 3: bf16 row-major with per-row inv scale (PV)
#pragma unroll
    for (int mi = 0; mi < 4; ++mi)
#pragma unroll
      for (int ni = 0; ni < 4; ++ni) {
        int cc = bx * BN + wc * 64 + ni * 16 + fcol;
#pragma unroll
        for (int r = 0; r < 4; ++r) {
          int rr = r0 + mi * 16 + r;
          o16[(size_t)rr * ldc + cc] = f32_bf16_rn(acc[mi][ni][r] * inv[rr]);
        }
      }
  }
}

// ---------------------------------------------------------------------------
extern "C" void kernel_launch(void* const* d_in, const int* in_sizes, int n_in,
                              void* d_out, int out_size, void* d_ws, size_t ws_size,
                              hipStream_t stream) {
  (void)in_sizes; (void)n_in; (void)out_size; (void)ws_size;
  const float* x     = (const float*)d_in[0];  // [4096][2048]
  const float* Wqkv  = (const float*)d_in[1];  // [6144][2048]
  const float* bqkv  = (const float*)d_in[2];  // [6144]
  const float* Wproj = (const float*)d_in[3];  // [2048][2048]
  const float* bproj = (const float*)d_in[4];  // [2048]
  float* out = (float*)d_out;                  // [4096][2048]

  char* w = (char*)d_ws;
  u16*   x2   = (u16*)w;                       // [4096][4096] [h|l]   @0          33.5MB
  u16*   W2   = (u16*)(w + 33554432);          // [4096][4096] [h|l] (Wq,Wk rows)  33.5MB
  u16*   q2   = (u16*)(w + 67108864);          // [4096][4096] [h|l]               33.5MB
  u16*   k2   = (u16*)(w + 100663296);         // [4096][4096] [h|l]               33.5MB
  u16*   vT   = (u16*)(w + 134217728);         // [2048][4096] v^T bf16            16.8MB
  u16*   Wv   = (u16*)(w + 150994944);         // [2048][2048] bf16                 8.4MB
  u16*   Wp   = (u16*)(w + 159383552);         // [2048][2048] bf16                 8.4MB
  float* inv  = (float*)(w + 167772160);       // [4096] f32                        16KB
  float* Smat = (float*)w;                     // [4096][4096] f32 (x2/W2 dead)    67.1MB
  u16*   P    = (u16*)(w + 67108864);          // [4096][4096] bf16 (q2 dead)      33.5MB
  u16*   ao   = (u16*)(w + 100663296);         // [4096][2048] bf16 (k2 dead)      16.8MB

  // 1) hi/lo splits: x, and q/k rows of Wqkv; plain casts: Wv, Wproj
  split2<<<2048, 256, 0, stream>>>(x,    x2, (size_t)4096 * 2048);
  split2<<<2048, 256, 0, stream>>>(Wqkv, W2, (size_t)4096 * 2048);
  cast_bf16_k<<<1024, 256, 0, stream>>>(Wqkv + (size_t)4096 * 2048, Wv, 2048 * 2048 / 4);
  cast_bf16_k<<<1024, 256, 0, stream>>>(Wproj, Wp, 2048 * 2048 / 4);

  // 2) qk-proj (3-term split, K=6144 logical): -> q2,k2 hi/lo (+bias)
  gemm_u<1, 1, 2, 0, true><<<dim3(32, 32), 256, 0, stream>>>(
      x2, 4096, W2, 4096, nullptr, nullptr, 0, q2, k2, bqkv, nullptr, 6144);

  // 3) v-proj (single bf16, K=2048): -> vT transposed (+bias)
  gemm_u<2, 0, 0, 0, true><<<dim3(16, 32), 256, 0, stream>>>(
      x2, 4096, Wv, 2048, nullptr, vT, 0, nullptr, nullptr, bqkv + 4096, nullptr, 2048);

  // 4) S = k @ q^T (causal blocks, 3-term split) -> f32
  gemm_u<0, 1, 2, 1, false><<<dim3(32, 32), 256, 0, stream>>>(
      k2, 4096, q2, 4096, Smat, nullptr, 4096, nullptr, nullptr, nullptr, nullptr, 6144);

  // 5) softmax rows -> P (unscaled exp, bf16) + inv[]
  softmax_causal<<<4096, 256, 0, stream>>>(Smat, P, inv, 4096);

  // 6) attn = (P @ v) * inv[row]  (K-limited per 128-row block) -> bf16
  gemm_u<3, 0, 0, 2, false><<<dim3(16, 32), 256, 0, stream>>>(
      P, 4096, vT, 4096, nullptr, ao, 2048, nullptr, nullptr, nullptr, inv, 4096);

  // 7) out = attn @ Wproj^T + bproj -> f32
  gemm_u<0, 0, 0, 0, true><<<dim3(16, 32), 256, 0, stream>>>(
      ao, 2048, Wp, 2048, out, nullptr, 2048, nullptr, nullptr, bproj, nullptr, 2048);
}

// Round 5
// 611.882 us; speedup vs baseline: 1.3642x; 1.1456x over previous
//
#include <hip/hip_runtime.h>
#include <stdint.h>
#include <math.h>

typedef unsigned short u16;
typedef __bf16 bf16x8 __attribute__((ext_vector_type(8)));
typedef float f32x4 __attribute__((ext_vector_type(4)));

__device__ __forceinline__ u16 f32_bf16_rn(float f) {
  uint32_t u = __float_as_uint(f);
  uint32_t r = (u + 0x7FFFu + ((u >> 16) & 1u)) >> 16;
  return (u16)r;
}
__device__ __forceinline__ float bf16_f32(u16 h) {
  return __uint_as_float(((uint32_t)h) << 16);
}

// async global->LDS, 16B per lane. LDS dest = wave-uniform base + lane*16.
__device__ __forceinline__ void async16(const u16* g, u16* l) {
  __builtin_amdgcn_global_load_lds(
      (__attribute__((address_space(1))) void*)(g),
      (__attribute__((address_space(3))) void*)(l), 16, 0, 0);
}

// ---------------------------------------------------------------------------
// fused prep: x -> x2 (hi|lo), Wqkv[0:4096] -> W2 (hi|lo),
// Wqkv[4096:6144] -> Wv bf16, Wproj -> Wp bf16. All float4-vectorized.
// ---------------------------------------------------------------------------
__global__ __launch_bounds__(256)
void prep(const float* __restrict__ x, const float* __restrict__ Wqkv,
          const float* __restrict__ Wproj,
          u16* __restrict__ x2, u16* __restrict__ W2,
          u16* __restrict__ Wv, u16* __restrict__ Wp) {
  const int stride = gridDim.x * blockDim.x;
  const int tid0 = blockIdx.x * blockDim.x + threadIdx.x;

  // split regions: in [R][2048] f32 (as 512 float4/row) -> out [R][4096] hi|lo
#pragma unroll
  for (int reg = 0; reg < 2; ++reg) {
    const float4* in4 = (const float4*)(reg == 0 ? x : Wqkv);
    u16* out = (reg == 0) ? x2 : W2;
    const int total4 = 4096 * 512;
    for (int i = tid0; i < total4; i += stride) {
      int r = i >> 9, c4 = i & 511;
      float4 f = in4[i];
      ushort4 h, l;
      h.x = f32_bf16_rn(f.x); l.x = f32_bf16_rn(f.x - bf16_f32(h.x));
      h.y = f32_bf16_rn(f.y); l.y = f32_bf16_rn(f.y - bf16_f32(h.y));
      h.z = f32_bf16_rn(f.z); l.z = f32_bf16_rn(f.z - bf16_f32(h.z));
      h.w = f32_bf16_rn(f.w); l.w = f32_bf16_rn(f.w - bf16_f32(h.w));
      *(ushort4*)&out[(size_t)r * 4096 + c4 * 4] = h;
      *(ushort4*)&out[(size_t)r * 4096 + 2048 + c4 * 4] = l;
    }
  }
  // cast regions: [2048][2048] f32 -> bf16
#pragma unroll
  for (int reg = 0; reg < 2; ++reg) {
    const float4* in4 = (const float4*)(reg == 0 ? Wqkv + (size_t)4096 * 2048 : Wproj);
    u16* out = (reg == 0) ? Wv : Wp;
    const int total4 = 2048 * 512;
    for (int i = tid0; i < total4; i += stride) {
      float4 f = in4[i];
      ushort4 o;
      o.x = f32_bf16_rn(f.x); o.y = f32_bf16_rn(f.y);
      o.z = f32_bf16_rn(f.z); o.w = f32_bf16_rn(f.w);
      ((ushort4*)out)[i] = o;
    }
  }
}

// ---------------------------------------------------------------------------
// single-pass causal row softmax: row cached in 16 VGPRs/thread.
// S f32 [4096][4096] -> P bf16 (UNSCALED exp), inv[row] = 1/sum.
// Row r valid cols 0..r, zero-fill to (r/128+1)*128 (PV Keff boundary).
// ---------------------------------------------------------------------------
__device__ __forceinline__ float waveMax(float v) {
#pragma unroll
  for (int o = 32; o > 0; o >>= 1) v = fmaxf(v, __shfl_xor(v, o));
  return v;
}
__device__ __forceinline__ float waveSum(float v) {
#pragma unroll
  for (int o = 32; o > 0; o >>= 1) v += __shfl_xor(v, o);
  return v;
}

__global__ __launch_bounds__(256)
void softmax1p(const float* __restrict__ S, u16* __restrict__ P,
               float* __restrict__ inv, int L) {
  const int row = blockIdx.x;
  const int tid = threadIdx.x;
  const int wave = tid >> 6, lane = tid & 63;
  const int n = row + 1;
  const int pad4 = (((row >> 7) + 1) << 7) >> 2;   // float4 slots to fill
  const float4* s4 = (const float4*)(S + (size_t)row * L);
  __shared__ float sred[8];

  float4 v[4];
  float m = -3.4e38f;
#pragma unroll
  for (int c = 0; c < 4; ++c) {
    int j4 = tid + c * 256;
    v[c] = s4[j4];                 // may read garbage beyond n; masked below
    int jb = j4 * 4;
    m = fmaxf(m, (jb + 0 < n) ? v[c].x : -3.4e38f);
    m = fmaxf(m, (jb + 1 < n) ? v[c].y : -3.4e38f);
    m = fmaxf(m, (jb + 2 < n) ? v[c].z : -3.4e38f);
    m = fmaxf(m, (jb + 3 < n) ? v[c].w : -3.4e38f);
  }
  m = waveMax(m);
  if (lane == 0) sred[wave] = m;
  __syncthreads();
  m = fmaxf(fmaxf(sred[0], sred[1]), fmaxf(sred[2], sred[3]));

  u16* p = P + (size_t)row * L;
  float sum = 0.0f;
#pragma unroll
  for (int c = 0; c < 4; ++c) {
    int j4 = tid + c * 256;
    if (j4 < pad4) {
      int jb = j4 * 4;
      float e0 = (jb + 0 < n) ? __expf(v[c].x - m) : 0.0f;
      float e1 = (jb + 1 < n) ? __expf(v[c].y - m) : 0.0f;
      float e2 = (jb + 2 < n) ? __expf(v[c].z - m) : 0.0f;
      float e3 = (jb + 3 < n) ? __expf(v[c].w - m) : 0.0f;
      ushort4 o;
      o.x = f32_bf16_rn(e0); o.y = f32_bf16_rn(e1);
      o.z = f32_bf16_rn(e2); o.w = f32_bf16_rn(e3);
      *(ushort4*)&p[jb] = o;
      sum += e0 + e1 + e2 + e3;
    }
  }
  sum = waveSum(sum);
  if (lane == 0) sred[4 + wave] = sum;
  __syncthreads();
  if (tid == 0) inv[row] = 1.0f / (sred[4] + sred[5] + sred[6] + sred[7]);
}

// ---------------------------------------------------------------------------
// K-remap for the 3-term bf16 split GEMM over physical [hi|lo] storage:
// mode 0: identity. mode 1: [h|l|h] (A side). mode 2: [h|h|l] (B side).
// ---------------------------------------------------------------------------
__device__ __forceinline__ int kmap(int mode, int t) {
  if (mode == 1) return (t < 32) ? t * 64 : (t < 64) ? 2048 + (t - 32) * 64 : (t - 64) * 64;
  if (mode == 2) return (t < 32) ? t * 64 : (t < 64) ? (t - 32) * 64 : 2048 + (t - 64) * 64;
  return t * 64;
}

// ---------------------------------------------------------------------------
// Unified 128x128 NT GEMM (proven m97 structure), BK=64, 4 waves, 4x4 frags
// of mfma_f32_16x16x32_bf16, XOR-swizzled LDS via pre-swizzled global source.
// 1D grid + bijective XCD chunk swizzle (m204), then:
//   GRID 0: bx = s%nxb, by = s/nxb. GRID 1: triangular (bx<=by). GRID 2:
//   rect with by reversed (long-K blocks dispatch first; PV).
// CAUSAL 2: Keff=by*128+128 (PV).
// EPI 0: f32 C (ldc) [+bias]. EPI 1: qk hi/lo split (+bias).
// EPI 2: vT transposed bf16 (+bias). EPI 3: bf16 row-major, row-scale inv[].
// ---------------------------------------------------------------------------
template<int EPI, int AMAP, int BMAP, int CAUSAL, bool HAS_BIAS, int GRID>
__global__ __launch_bounds__(256)
void gemm_u(const u16* __restrict__ A, int lda, const u16* __restrict__ B, int ldb,
            float* __restrict__ Cf, u16* __restrict__ o16, int ldc,
            u16* __restrict__ eq, u16* __restrict__ ek,
            const float* __restrict__ bias, const float* __restrict__ inv,
            int K, int nxb) {
  constexpr int BM = 128, BN = 128, BK = 64;
  __shared__ u16 As[BM * BK];
  __shared__ u16 Bs[BN * BK];

  // --- grid decode: XCD chunk swizzle, then shape-specific mapping ---
  const int ngrid = gridDim.x;
  const int q8 = ngrid >> 3, r8 = ngrid & 7;
  const int xcd = blockIdx.x & 7, ord = blockIdx.x >> 3;
  const int s = (xcd < r8 ? xcd * (q8 + 1) : r8 * (q8 + 1) + (xcd - r8) * q8) + ord;
  int bx, by;
  if (GRID == 1) {
    by = (int)((sqrtf(8.0f * (float)s + 1.0f) - 1.0f) * 0.5f);
    while ((by + 1) * (by + 2) / 2 <= s) ++by;
    while (by * (by + 1) / 2 > s) --by;
    bx = s - by * (by + 1) / 2;
  } else if (GRID == 2) {
    bx = s % nxb;
    by = (ngrid / nxb) - 1 - s / nxb;
  } else {
    bx = s % nxb;
    by = s / nxb;
  }

  const int Keff = (CAUSAL == 2) ? (by * BM + BM) : K;

  const int tid = threadIdx.x;
  const int wave = tid >> 6, lane = tid & 63;
  const int wr = wave >> 1, wc = wave & 1;

  const int srow = lane >> 3;
  const int scol = ((lane & 7) ^ srow) << 3;
  const u16* Ag = A + (size_t)(by * BM + wave * 8 + srow) * lda + scol;
  const u16* Bg = B + (size_t)(bx * BN + wave * 8 + srow) * ldb + scol;
  u16* AsW = As + wave * 8 * BK;
  u16* BsW = Bs + wave * 8 * BK;

  f32x4 zero = {0.0f, 0.0f, 0.0f, 0.0f};
  f32x4 acc[4][4];
#pragma unroll
  for (int i = 0; i < 4; ++i)
#pragma unroll
    for (int j = 0; j < 4; ++j) acc[i][j] = zero;

  for (int k0 = 0; k0 < Keff; k0 += BK) {
    const int t = k0 >> 6;
    const int kca = kmap(AMAP, t);
    const int kcb = kmap(BMAP, t);
#pragma unroll
    for (int it = 0; it < 4; ++it) {
      async16(Ag + (size_t)it * 32 * lda + kca, AsW + it * 32 * BK);
      async16(Bg + (size_t)it * 32 * ldb + kcb, BsW + it * 32 * BK);
    }
    __syncthreads();

#pragma unroll
    for (int kk = 0; kk < 2; ++kk) {
      bf16x8 af[4], bb[4];
      int col = lane & 15;
      int sl = kk * 4 + (lane >> 4);
#pragma unroll
      for (int mi = 0; mi < 4; ++mi) {
        int row = wr * 64 + mi * 16 + col;
        af[mi] = *(const bf16x8*)&As[row * BK + ((sl ^ (row & 7)) << 3)];
      }
#pragma unroll
      for (int ni = 0; ni < 4; ++ni) {
        int row = wc * 64 + ni * 16 + col;
        bb[ni] = *(const bf16x8*)&Bs[row * BK + ((sl ^ (row & 7)) << 3)];
      }
#pragma unroll
      for (int mi = 0; mi < 4; ++mi)
#pragma unroll
        for (int ni = 0; ni < 4; ++ni)
          acc[mi][ni] = __builtin_amdgcn_mfma_f32_16x16x32_bf16(
              af[mi], bb[ni], acc[mi][ni], 0, 0, 0);
    }
    __syncthreads();
  }

  // epilogue: D layout col = lane&15, row = (lane>>4)*4 + r
  const int fcol = lane & 15;
  const int r0 = by * BM + wr * 64 + ((lane >> 4) << 2);

  if (EPI == 0) {
#pragma unroll
    for (int mi = 0; mi < 4; ++mi)
#pragma unroll
      for (int ni = 0; ni < 4; ++ni) {
        int cc = bx * BN + wc * 64 + ni * 16 + fcol;
        float bv = HAS_BIAS ? bias[cc] : 0.0f;
#pragma unroll
        for (int r = 0; r < 4; ++r)
          Cf[(size_t)(r0 + mi * 16 + r) * ldc + cc] = acc[mi][ni][r] + bv;
      }
  } else if (EPI == 1) {
    // qk epilogue: global col in [0,4096); <2048 -> q2, else k2; hi/lo split
    const int colb = bx * BN + wc * 64;       // uniform per wave
    u16* dst = (colb < 2048) ? eq : ek;
    const int cbase = colb & 2047;
#pragma unroll
    for (int mi = 0; mi < 4; ++mi)
#pragma unroll
      for (int ni = 0; ni < 4; ++ni) {
        const int cc = cbase + ni * 16 + fcol;
        const float bv = HAS_BIAS ? bias[colb + ni * 16 + fcol] : 0.0f;
#pragma unroll
        for (int r = 0; r < 4; ++r) {
          float v = acc[mi][ni][r] + bv;
          u16 hi = f32_bf16_rn(v);
          u16 lo = f32_bf16_rn(v - bf16_f32(hi));
          size_t ro = (size_t)(r0 + mi * 16 + r) * 4096;
          dst[ro + cc] = hi;
          dst[ro + 2048 + cc] = lo;
        }
      }
  } else if (EPI == 2) {
    // vT epilogue: out[vc][seq] bf16, vc in [0,2048)
#pragma unroll
    for (int mi = 0; mi < 4; ++mi)
#pragma unroll
      for (int ni = 0; ni < 4; ++ni) {
        const int vc = bx * BN + wc * 64 + ni * 16 + fcol;
        const float bv = HAS_BIAS ? bias[vc] : 0.0f;
        ushort4 o;
        o.x = f32_bf16_rn(acc[mi][ni][0] + bv);
        o.y = f32_bf16_rn(acc[mi][ni][1] + bv);
        o.z = f32_bf16_rn(acc[mi][ni][2] + bv);
        o.w = f32_bf16_rn(acc[mi][ni][3] + bv);
        *(ushort4*)&o16[(size_t)vc * 4096 + r0 + mi * 16] = o;
      }
  } else {
    // EPI 3: bf16 row-major with per-row inv scale (PV)
#pragma unroll
    for (int mi = 0; mi < 4; ++mi)
#pragma unroll
      for (int ni = 0; ni < 4; ++ni) {
        int cc = bx * BN + wc * 64 + ni * 16 + fcol;
#pragma unroll
        for (int r = 0; r < 4; ++r) {
          int rr = r0 + mi * 16 + r;
          o16[(size_t)rr * ldc + cc] = f32_bf16_rn(acc[mi][ni][r] * inv[rr]);
        }
      }
  }
}

// ---------------------------------------------------------------------------
extern "C" void kernel_launch(void* const* d_in, const int* in_sizes, int n_in,
                              void* d_out, int out_size, void* d_ws, size_t ws_size,
                              hipStream_t stream) {
  (void)in_sizes; (void)n_in; (void)out_size; (void)ws_size;
  const float* x     = (const float*)d_in[0];  // [4096][2048]
  const float* Wqkv  = (const float*)d_in[1];  // [6144][2048]
  const float* bqkv  = (const float*)d_in[2];  // [6144]
  const float* Wproj = (const float*)d_in[3];  // [2048][2048]
  const float* bproj = (const float*)d_in[4];  // [2048]
  float* out = (float*)d_out;                  // [4096][2048]

  char* w = (char*)d_ws;
  u16*   x2   = (u16*)w;                       // [4096][4096] [h|l]   @0          33.5MB
  u16*   W2   = (u16*)(w + 33554432);          // [4096][4096] [h|l] (Wq,Wk rows)  33.5MB
  u16*   q2   = (u16*)(w + 67108864);          // [4096][4096] [h|l]               33.5MB
  u16*   k2   = (u16*)(w + 100663296);         // [4096][4096] [h|l]               33.5MB
  u16*   vT   = (u16*)(w + 134217728);         // [2048][4096] v^T bf16            16.8MB
  u16*   Wv   = (u16*)(w + 150994944);         // [2048][2048] bf16                 8.4MB
  u16*   Wp   = (u16*)(w + 159383552);         // [2048][2048] bf16                 8.4MB
  float* inv  = (float*)(w + 167772160);       // [4096] f32                        16KB
  float* Smat = (float*)w;                     // [4096][4096] f32 (x2/W2 dead)    67.1MB
  u16*   P    = (u16*)(w + 67108864);          // [4096][4096] bf16 (q2 dead)      33.5MB
  u16*   ao   = (u16*)(w + 100663296);         // [4096][2048] bf16 (k2 dead)      16.8MB

  // 1) fused prep: x2, W2 (hi|lo splits) + Wv, Wp (bf16 casts)
  prep<<<1024, 256, 0, stream>>>(x, Wqkv, Wproj, x2, W2, Wv, Wp);

  // 2) qk-proj (3-term split, K=6144 logical): -> q2,k2 hi/lo (+bias)
  gemm_u<1, 1, 2, 0, true, 0><<<1024, 256, 0, stream>>>(
      x2, 4096, W2, 4096, nullptr, nullptr, 0, q2, k2, bqkv, nullptr, 6144, 32);

  // 3) v-proj (single bf16, K=2048): -> vT transposed (+bias)
  gemm_u<2, 0, 0, 0, true, 0><<<512, 256, 0, stream>>>(
      x2, 4096, Wv, 2048, nullptr, vT, 0, nullptr, nullptr, bqkv + 4096, nullptr, 2048, 16);

  // 4) S = k @ q^T (compact triangular grid, 3-term split) -> f32
  gemm_u<0, 1, 2, 0, false, 1><<<528, 256, 0, stream>>>(
      k2, 4096, q2, 4096, Smat, nullptr, 4096, nullptr, nullptr, nullptr, nullptr, 6144, 32);

  // 5) single-pass softmax -> P (unscaled exp, bf16) + inv[]
  softmax1p<<<4096, 256, 0, stream>>>(Smat, P, inv, 4096);

  // 6) attn = (P @ v) * inv[row]  (K-limited, long-K blocks first) -> bf16
  gemm_u<3, 0, 0, 2, false, 2><<<512, 256, 0, stream>>>(
      P, 4096, vT, 4096, nullptr, ao, 2048, nullptr, nullptr, nullptr, inv, 4096, 16);

  // 7) out = attn @ Wproj^T + bproj -> f32
  gemm_u<0, 0, 0, 0, true, 0><<<512, 256, 0, stream>>>(
      ao, 2048, Wp, 2048, out, nullptr, 2048, nullptr, nullptr, bproj, nullptr, 2048, 16);
}